// Round 18
// baseline (849.686 us; speedup 1.0000x reference)
//
#include <hip/hip_runtime.h>
#include <hip/hip_bf16.h>

typedef __attribute__((ext_vector_type(8))) short bf16x8;
typedef __attribute__((ext_vector_type(4))) float f32x4;
typedef __attribute__((ext_vector_type(2))) float f32x2;
typedef __attribute__((ext_vector_type(4))) unsigned short u16x4;

#define HB 256      // hidden
#define G3 768      // 3*H
#define SQ 512      // seq len
#define NBATCH 4
#define NV 32000
#define NPAIR 2000  // 4000 logits tiles / 2 per block

__device__ __forceinline__ unsigned short f2bf(float f) {
    unsigned int u = __float_as_uint(f);
    u = u + 0x7FFFu + ((u >> 16) & 1u);   // RNE
    return (unsigned short)(u >> 16);
}

// ---------------------------------------------------------------- K0: prep
// (a) W_ih^T fp32 [256][768]; (b) W_hh -> bf16 A-frags [w:8][g:3][rt:2][c:8][l][i]
// (c) zero the producer-consumer flags (re-zeroed every launch/replay).
__global__ void k_prep(const float* __restrict__ W_ih, const float* __restrict__ W_hh,
                       float* __restrict__ w_ihT, unsigned short* __restrict__ wfrag,
                       int* flags) {
    if (flags && blockIdx.x == 0 && threadIdx.x == 0) { flags[0] = 0; flags[1] = 0; }
    int stride = gridDim.x * blockDim.x;
    int tid = blockIdx.x * blockDim.x + threadIdx.x;
    for (int e = tid; e < G3 * HB; e += stride) {
        int k = e / G3, g = e - k * G3;
        w_ihT[e] = W_ih[g * HB + k];
    }
    for (int e = tid; e < G3 * HB; e += stride) {
        int i = e & 7, l = (e >> 3) & 63, c = (e >> 9) & 7, rt = (e >> 12) & 1;
        int q = e >> 13;              // 0..23
        int t = q % 3, w = q / 3;     // gate, wave
        int row = t * 256 + 32 * w + 16 * rt + (l & 15);
        int kk = 32 * c + 8 * (l >> 4) + i;
        wfrag[e] = f2bf(W_hh[row * HB + kk]);
    }
}

// ---------------------------------------------------------------- K1: embed + xp
__global__ __launch_bounds__(256) void k_embed_xp(
        const int* __restrict__ x, const float* __restrict__ emb,
        const float* __restrict__ w_ihT, const float* __restrict__ b_ih,
        const float* __restrict__ b_hh, float* __restrict__ xp) {
    __shared__ float e[8][HB];
    int tid = threadIdx.x;
    int tok0 = blockIdx.x * 8;
    {
        int s = tid >> 5, k0 = (tid & 31) * 8;
        long idx = x[tok0 + s];
        const float* src = emb + idx * (long)HB + k0;
        f32x4 a = *(const f32x4*)src, bq = *(const f32x4*)(src + 4);
        *(f32x4*)&e[s][k0] = a;
        *(f32x4*)&e[s][k0 + 4] = bq;
    }
    __syncthreads();
    #pragma unroll
    for (int it = 0; it < 3; ++it) {
        int gg = tid + it * 256;
        float acc[8] = {0.f, 0.f, 0.f, 0.f, 0.f, 0.f, 0.f, 0.f};
        for (int k = 0; k < HB; k += 4) {
            float w0 = w_ihT[(k + 0) * G3 + gg];
            float w1 = w_ihT[(k + 1) * G3 + gg];
            float w2 = w_ihT[(k + 2) * G3 + gg];
            float w3 = w_ihT[(k + 3) * G3 + gg];
            #pragma unroll
            for (int s = 0; s < 8; ++s) {
                f32x4 ev = *(const f32x4*)&e[s][k];
                acc[s] += w0 * ev.x + w1 * ev.y + w2 * ev.z + w3 * ev.w;
            }
        }
        float bias = b_ih[gg] + (gg < 512 ? b_hh[gg] : 0.f);
        #pragma unroll
        for (int s = 0; s < 8; ++s)
            xp[(size_t)(tok0 + s) * G3 + gg] = acc[s] + bias;
    }
}

// ------------------------------------------------ logits tile (r16 128x128)
__device__ __forceinline__ void logits_tile(
        const unsigned short* __restrict__ rnn, const unsigned short* __restrict__ woutbf,
        const float* __restrict__ b_out, const int* __restrict__ x,
        float* __restrict__ out, int bx, int by, int ltid) {
    int wv = ltid >> 6, l = ltid & 63;
    int wm = wv >> 1, wn = wv & 1;
    int c15 = l & 15, hi = l >> 4;
    int m0 = by * 128 + wm * 64;
    int n0 = bx * 128 + wn * 64;

    const f32x4 zz = {0.f, 0.f, 0.f, 0.f};
    f32x4 acc[4][4];
    #pragma unroll
    for (int i = 0; i < 4; ++i)
        #pragma unroll
        for (int j = 0; j < 4; ++j) acc[i][j] = zz;

    #pragma unroll
    for (int c = 0; c < 8; ++c) {
        bf16x8 af[4], bfr[4];
        #pragma unroll
        for (int rt = 0; rt < 4; ++rt)
            af[rt] = *(const bf16x8*)(rnn + (size_t)(m0 + rt * 16 + c15) * HB + 32 * c + 8 * hi);
        #pragma unroll
        for (int ct = 0; ct < 4; ++ct)
            bfr[ct] = *(const bf16x8*)(woutbf + (size_t)(n0 + ct * 16 + c15) * HB + 32 * c + 8 * hi);
        #pragma unroll
        for (int rt = 0; rt < 4; ++rt)
            #pragma unroll
            for (int ct = 0; ct < 4; ++ct)
                acc[rt][ct] = __builtin_amdgcn_mfma_f32_16x16x32_bf16(af[rt], bfr[ct], acc[rt][ct], 0, 0, 0);
    }

    float bo[4];
    #pragma unroll
    for (int ct = 0; ct < 4; ++ct) bo[ct] = b_out[n0 + ct * 16 + c15];

    const float NEGINF = -__builtin_inff();
    #pragma unroll
    for (int rt = 0; rt < 4; ++rt) {
        #pragma unroll
        for (int j = 0; j < 4; ++j) {
            int m = m0 + rt * 16 + 4 * hi + j;
            int tt = m & (SQ - 1);
            bool bad = (tt > 0) && (x[m - 1] == 0);
            float* orow = out + (size_t)m * NV;
            #pragma unroll
            for (int ct = 0; ct < 4; ++ct) {
                int v = n0 + ct * 16 + c15;
                float val = acc[rt][ct][j] + bo[ct];
                if (bad && v >= 3) val = NEGINF;
                orow[v] = val;
            }
        }
    }
}

// ---------------------------------------------------------------- K2: main
// OVL=1: grid 256 == exact co-residency capacity (1x512-thr block/CU at
// waves_per_eu(2,2)) -> all blocks resident, no dispatch-order deadlock.
//   block 0:      r14/r16 GRU (576 us proven) + release-store progress flag
//                 every 64 steps (vmcnt drain -> barrier -> wbl2+store).
//   blocks 1-255: woutbf conversion + handshake, then 2 logits tiles per
//                 block, spinning (relaxed poll + s_sleep, acquire fence on
//                 exit -> buffer_inv) until prog >= ((by&3)+1)*128.
// OVL=0 fallback (tiny ws): grid 1, GRU only; logits launched separately.
template <int OVL>
__global__ __attribute__((amdgpu_waves_per_eu(2, 2))) __launch_bounds__(512)
void k_main(const float* __restrict__ xp, const unsigned short* __restrict__ wfrag,
            const float* __restrict__ b_hh, unsigned short* __restrict__ rnn,
            const float* __restrict__ W_out, unsigned short* __restrict__ woutbf,
            const float* __restrict__ b_out, const int* __restrict__ x,
            float* __restrict__ out, int* flags) {
    __shared__ unsigned short hbf[2][NBATCH][HB];    // 4096 B, XOR-swizzled
    int tid = threadIdx.x;

    if (blockIdx.x != 0) {
        if (!OVL) return;
        // -------- phase 1: woutbf conversion across 255 workers --------
        {
            const f32x4* src = (const f32x4*)W_out;
            u16x4* dst = (u16x4*)woutbf;
            int start = (int)(blockIdx.x - 1) * 512 + tid;
            for (int qd = start; qd < NV * HB / 4; qd += 255 * 512) {
                f32x4 v = src[qd];
                u16x4 o;
                o[0] = f2bf(v.x); o[1] = f2bf(v.y); o[2] = f2bf(v.z); o[3] = f2bf(v.w);
                dst[qd] = o;
            }
        }
        __syncthreads();   // drains vmcnt: all this block's conv stores done
        if (tid == 0)
            __hip_atomic_fetch_add(&flags[1], 1, __ATOMIC_ACQ_REL, __HIP_MEMORY_SCOPE_AGENT);
        while (__hip_atomic_load(&flags[1], __ATOMIC_RELAXED, __HIP_MEMORY_SCOPE_AGENT) < 255)
            __builtin_amdgcn_s_sleep(8);
        __builtin_amdgcn_fence(__ATOMIC_ACQUIRE, "agent");

        // -------- phase 2: logits tiles, gated on GRU progress --------
        int half = tid >> 8, ltid = tid & 255;
        for (int p = (int)(blockIdx.x - 1); p < NPAIR; p += 255) {
            int tile = 2 * p + half;
            int by = tile / 250, bx = tile - by * 250;
            int need = ((by & 3) + 1) * 128;
            while (__hip_atomic_load(&flags[0], __ATOMIC_RELAXED, __HIP_MEMORY_SCOPE_AGENT) < need)
                __builtin_amdgcn_s_sleep(8);
            __builtin_amdgcn_fence(__ATOMIC_ACQUIRE, "agent");
            logits_tile(rnn, woutbf, b_out, x, out, bx, by, ltid);
        }
        return;
    }

    // ---------------- block 0: GRU scan (exact r14/r16 body) ----------------
    int w = tid >> 6, l = tid & 63;
    int c15 = l & 15, hi = l >> 4;
    int b4 = c15 & 3;
    int q = c15 >> 2;
    int rt = q & 1, jh = q >> 1;
    int swz = (b4 & 1) << 6;

    bf16x8 Arz[2][2][8];
    bf16x8 An[2][8];
    #pragma unroll
    for (int g = 0; g < 2; ++g)
        #pragma unroll
        for (int r2 = 0; r2 < 2; ++r2)
            #pragma unroll
            for (int c = 0; c < 8; ++c) {
                Arz[g][r2][c] = ((const bf16x8*)wfrag)[(((w * 3 + g) * 2 + r2) * 8 + c) * 64 + l];
                asm volatile("" : "+a"(Arz[g][r2][c]));
            }
    #pragma unroll
    for (int r2 = 0; r2 < 2; ++r2)
        #pragma unroll
        for (int c = 0; c < 8; ++c) {
            An[r2][c] = ((const bf16x8*)wfrag)[(((w * 3 + 2) * 2 + r2) * 8 + c) * 64 + l];
            asm volatile("" : "+v"(An[r2][c]));
        }

    for (int k = tid; k < 2 * NBATCH * HB; k += 512) ((unsigned short*)hbf)[k] = 0;

    int row0 = 32 * w + 16 * rt + 4 * hi + 2 * jh;   // lane's 2 rows
    f32x2 bn = *(const f32x2*)&b_hh[512 + row0];
    float H0 = 0.f, H1 = 0.f;
    const f32x4 zz = {0.f, 0.f, 0.f, 0.f};

    const float* xpb = xp + (size_t)b4 * SQ * G3 + row0;
    unsigned short* rnb = rnn + (size_t)b4 * SQ * HB + row0;
    const char* rdb = (const char*)hbf + b4 * 512;
    char* wrb = (char*)hbf + b4 * 512 + ((row0 * 2) ^ swz);
    __syncthreads();

    for (int t = 0; t < SQ; ++t) {
        int cur = (t & 1) << 11, nxt = cur ^ 2048;

        f32x2 xr = *(const f32x2*)(xpb);
        f32x2 xz = *(const f32x2*)(xpb + 256);
        f32x2 xn = *(const f32x2*)(xpb + 512);

        f32x4 a0 = zz, a1 = zz, a2 = zz, a3 = zz, a4 = zz, a5 = zz;
        #pragma unroll
        for (int c = 0; c < 8; ++c) {
            bf16x8 Bf = *(const bf16x8*)(rdb + cur + ((64 * c + 16 * hi) ^ swz));
            asm("v_mfma_f32_16x16x32_bf16 %0, %1, %2, %0" : "+v"(a0) : "a"(Arz[0][0][c]), "v"(Bf));
            asm("v_mfma_f32_16x16x32_bf16 %0, %1, %2, %0" : "+v"(a1) : "a"(Arz[0][1][c]), "v"(Bf));
            asm("v_mfma_f32_16x16x32_bf16 %0, %1, %2, %0" : "+v"(a2) : "a"(Arz[1][0][c]), "v"(Bf));
            asm("v_mfma_f32_16x16x32_bf16 %0, %1, %2, %0" : "+v"(a3) : "a"(Arz[1][1][c]), "v"(Bf));
            a4 = __builtin_amdgcn_mfma_f32_16x16x32_bf16(An[0][c], Bf, a4, 0, 0, 0);
            a5 = __builtin_amdgcn_mfma_f32_16x16x32_bf16(An[1][c], Bf, a5, 0, 0, 0);
        }
        __builtin_amdgcn_sched_barrier(0);
        asm volatile("s_nop 7\n\ts_nop 7");
        __builtin_amdgcn_sched_barrier(0);

        bool brt = rt != 0, bjh = jh != 0;
        f32x4 vr = brt ? a1 : a0;
        f32x4 vz = brt ? a3 : a2;
        f32x4 vn = brt ? a5 : a4;
        float sr0 = bjh ? vr.z : vr.x, sr1 = bjh ? vr.w : vr.y;
        float sz0 = bjh ? vz.z : vz.x, sz1 = bjh ? vz.w : vz.y;
        float sn0 = bjh ? vn.z : vn.x, sn1 = bjh ? vn.w : vn.y;

        float r0 = __builtin_amdgcn_rcpf(1.f + __expf(-(xr.x + sr0)));
        float z0 = __builtin_amdgcn_rcpf(1.f + __expf(-(xz.x + sz0)));
        float n0 = 1.f - 2.f * __builtin_amdgcn_rcpf(__expf(2.f * (xn.x + r0 * (sn0 + bn.x))) + 1.f);
        float h0 = (1.f - z0) * n0 + z0 * H0;
        H0 = h0;
        float r1 = __builtin_amdgcn_rcpf(1.f + __expf(-(xr.y + sr1)));
        float z1 = __builtin_amdgcn_rcpf(1.f + __expf(-(xz.y + sz1)));
        float n1 = 1.f - 2.f * __builtin_amdgcn_rcpf(__expf(2.f * (xn.y + r1 * (sn1 + bn.y))) + 1.f);
        float h1 = (1.f - z1) * n1 + z1 * H1;
        H1 = h1;

        unsigned int pk;
        asm("v_cvt_pk_bf16_f32 %0, %1, %2" : "=v"(pk) : "v"(h0), "v"(h1));
        *(unsigned int*)(wrb + nxt) = pk;        // LDS h for next step
        *(unsigned int*)rnb = pk;                // global rnn

        // raw barrier; on signal steps also drain vmcnt so all waves' rnn
        // stores for steps <= t are in L2 before the release flush.
        if (OVL && ((t & 63) == 63))
            asm volatile("s_waitcnt vmcnt(0) lgkmcnt(0)" ::: "memory");
        else
            asm volatile("s_waitcnt lgkmcnt(0)" ::: "memory");
        __builtin_amdgcn_sched_barrier(0);
        __builtin_amdgcn_s_barrier();
        if (OVL && ((t & 63) == 63) && tid == 0)
            __hip_atomic_store(&flags[0], t + 1, __ATOMIC_RELEASE, __HIP_MEMORY_SCOPE_AGENT);

        xpb += G3;
        rnb += HB;
    }
}

// ---------------------------------------------------------------- K3: logits
// Fallback only (tiny ws): r16 config, converting W_out fp32 in-kernel.
__global__ __launch_bounds__(256) void k_logits_fb(
        const unsigned short* __restrict__ rnn, const float* __restrict__ woutf,
        const float* __restrict__ b_out, const int* __restrict__ x,
        float* __restrict__ out) {
    int fid = blockIdx.x;
    int g = (fid & 7) * 500 + (fid >> 3);
    int bx = g >> 4, by = g & 15;

    int tid = threadIdx.x;
    int wv = tid >> 6, l = tid & 63;
    int wm = wv >> 1, wn = wv & 1;
    int c15 = l & 15, hi = l >> 4;
    int m0 = by * 128 + wm * 64;
    int n0 = bx * 128 + wn * 64;

    const f32x4 zz = {0.f, 0.f, 0.f, 0.f};
    f32x4 acc[4][4];
    #pragma unroll
    for (int i = 0; i < 4; ++i)
        #pragma unroll
        for (int j = 0; j < 4; ++j) acc[i][j] = zz;

    #pragma unroll
    for (int c = 0; c < 8; ++c) {
        bf16x8 af[4], bfr[4];
        #pragma unroll
        for (int rt = 0; rt < 4; ++rt)
            af[rt] = *(const bf16x8*)(rnn + (size_t)(m0 + rt * 16 + c15) * HB + 32 * c + 8 * hi);
        #pragma unroll
        for (int ct = 0; ct < 4; ++ct) {
            const float* s = woutf + (size_t)(n0 + ct * 16 + c15) * HB + 32 * c + 8 * hi;
            f32x4 lo = *(const f32x4*)s, hi4 = *(const f32x4*)(s + 4);
            bf16x8 bb;
            #pragma unroll
            for (int qq = 0; qq < 4; ++qq) bb[qq] = (short)f2bf(lo[qq]);
            #pragma unroll
            for (int qq = 0; qq < 4; ++qq) bb[4 + qq] = (short)f2bf(hi4[qq]);
            bfr[ct] = bb;
        }
        #pragma unroll
        for (int rt = 0; rt < 4; ++rt)
            #pragma unroll
            for (int ct = 0; ct < 4; ++ct)
                acc[rt][ct] = __builtin_amdgcn_mfma_f32_16x16x32_bf16(af[rt], bfr[ct], acc[rt][ct], 0, 0, 0);
    }

    float bo[4];
    #pragma unroll
    for (int ct = 0; ct < 4; ++ct) bo[ct] = b_out[n0 + ct * 16 + c15];

    const float NEGINF = -__builtin_inff();
    #pragma unroll
    for (int rt = 0; rt < 4; ++rt) {
        #pragma unroll
        for (int j = 0; j < 4; ++j) {
            int m = m0 + rt * 16 + 4 * hi + j;
            int tt = m & (SQ - 1);
            bool bad = (tt > 0) && (x[m - 1] == 0);
            float* orow = out + (size_t)m * NV;
            #pragma unroll
            for (int ct = 0; ct < 4; ++ct) {
                int v = n0 + ct * 16 + c15;
                float val = acc[rt][ct][j] + bo[ct];
                if (bad && v >= 3) val = NEGINF;
                orow[v] = val;
            }
        }
    }
}

extern "C" void kernel_launch(void* const* d_in, const int* in_sizes, int n_in,
                              void* d_out, int out_size, void* d_ws, size_t ws_size,
                              hipStream_t stream) {
    const int*   x     = (const int*)d_in[0];
    const float* emb   = (const float*)d_in[1];
    const float* W_ih  = (const float*)d_in[2];
    const float* W_hh  = (const float*)d_in[3];
    const float* b_ih  = (const float*)d_in[4];
    const float* b_hh  = (const float*)d_in[5];
    const float* W_out = (const float*)d_in[6];
    const float* b_out = (const float*)d_in[7];
    float* out = (float*)d_out;

    char* ws = (char*)d_ws;
    float*          xp     = (float*)(ws);                       // 6,291,456 B
    float*          w_ihT  = (float*)(ws + 6291456);             // 786,432 B
    unsigned short* wfrag  = (unsigned short*)(ws + 7077888);    // 393,216 B
    unsigned short* rnn    = (unsigned short*)(ws + 7471104);    // 1,048,576 B
    unsigned short* woutbf = (unsigned short*)(ws + 8519680);    // 16,384,000 B
    int*            flags  = (int*)(ws + 24903680);              // 2 ints
    int ovl = (ws_size >= (size_t)(24903680 + 64)) ? 1 : 0;

    k_prep<<<512, 256, 0, stream>>>(W_ih, W_hh, w_ihT, wfrag, ovl ? flags : nullptr);
    k_embed_xp<<<256, 256, 0, stream>>>(x, emb, w_ihT, b_ih, b_hh, xp);
    if (ovl) {
        k_main<1><<<256, 512, 0, stream>>>(xp, wfrag, b_hh, rnn, W_out, woutbf,
                                           b_out, x, out, flags);
    } else {
        k_main<0><<<1, 512, 0, stream>>>(xp, wfrag, b_hh, rnn, W_out, woutbf,
                                         b_out, x, out, nullptr);
        k_logits_fb<<<4000, 256, 0, stream>>>(rnn, W_out, b_out, x, out);
    }
}

// Round 19
// 752.462 us; speedup vs baseline: 1.1292x; 1.1292x over previous
//
#include <hip/hip_runtime.h>
#include <hip/hip_bf16.h>

typedef __attribute__((ext_vector_type(8))) short bf16x8;
typedef __attribute__((ext_vector_type(4))) float f32x4;
typedef __attribute__((ext_vector_type(2))) float f32x2;
typedef __attribute__((ext_vector_type(4))) unsigned short u16x4;

#define HB 256      // hidden
#define G3 768      // 3*H
#define SQ 512      // seq len
#define NBATCH 4
#define NV 32000

__device__ __forceinline__ unsigned short f2bf(float f) {
    unsigned int u = __float_as_uint(f);
    u = u + 0x7FFFu + ((u >> 16) & 1u);   // RNE
    return (unsigned short)(u >> 16);
}

// ---------------------------------------------------------------- K0: prep
// (a) W_ih^T fp32 [256][768] for coalesced K1 loads
// (b) W_hh -> bf16 MFMA A-fragments for the 8-wave k_gru:
//     layout [w:8][g:3][rt:2][c:8][lane:64][i:8]
// (woutbf conversion lives in k_gru's launch: runs on idle CUs there)
__global__ void k_prep(const float* __restrict__ W_ih, const float* __restrict__ W_hh,
                       float* __restrict__ w_ihT, unsigned short* __restrict__ wfrag) {
    int stride = gridDim.x * blockDim.x;
    int tid = blockIdx.x * blockDim.x + threadIdx.x;
    for (int e = tid; e < G3 * HB; e += stride) {
        int k = e / G3, g = e - k * G3;
        w_ihT[e] = W_ih[g * HB + k];
    }
    for (int e = tid; e < G3 * HB; e += stride) {
        int i = e & 7, l = (e >> 3) & 63, c = (e >> 9) & 7, rt = (e >> 12) & 1;
        int q = e >> 13;              // 0..23
        int t = q % 3, w = q / 3;     // gate, wave
        int row = t * 256 + 32 * w + 16 * rt + (l & 15);
        int kk = 32 * c + 8 * (l >> 4) + i;
        wfrag[e] = f2bf(W_hh[row * HB + kk]);
    }
}

// ---------------------------------------------------------------- K1: embed + xp
// 512 blocks x 4 tokens (2 blocks/CU -> 2 waves/SIMD of TLP)
__global__ __launch_bounds__(256) void k_embed_xp(
        const int* __restrict__ x, const float* __restrict__ emb,
        const float* __restrict__ w_ihT, const float* __restrict__ b_ih,
        const float* __restrict__ b_hh, float* __restrict__ xp) {
    __shared__ float e[4][HB];
    int tid = threadIdx.x;
    int tok0 = blockIdx.x * 4;
    if (tid < 128) {
        int s = tid >> 5, k0 = (tid & 31) * 8;
        long idx = x[tok0 + s];
        const float* src = emb + idx * (long)HB + k0;
        f32x4 a = *(const f32x4*)src, bq = *(const f32x4*)(src + 4);
        *(f32x4*)&e[s][k0] = a;
        *(f32x4*)&e[s][k0 + 4] = bq;
    }
    __syncthreads();
    #pragma unroll
    for (int it = 0; it < 3; ++it) {
        int gg = tid + it * 256;
        float acc[4] = {0.f, 0.f, 0.f, 0.f};
        for (int k = 0; k < HB; k += 4) {
            float w0 = w_ihT[(k + 0) * G3 + gg];
            float w1 = w_ihT[(k + 1) * G3 + gg];
            float w2 = w_ihT[(k + 2) * G3 + gg];
            float w3 = w_ihT[(k + 3) * G3 + gg];
            #pragma unroll
            for (int s = 0; s < 4; ++s) {
                f32x4 ev = *(const f32x4*)&e[s][k];
                acc[s] += w0 * ev.x + w1 * ev.y + w2 * ev.z + w3 * ev.w;
            }
        }
        float bias = b_ih[gg] + (gg < 512 ? b_hh[gg] : 0.f);
        #pragma unroll
        for (int s = 0; s < 4; ++s)
            xp[(size_t)(tok0 + s) * G3 + gg] = acc[s] + bias;
    }
}

// ---------------------------------------------------------------- K2: GRU scan
// Block 0: EXACT r14 GRU (576 us proven; 8 waves, 2/SIMD, exact 256-reg/wave:
// r/z frags 128 AGPR via asm "a", n frags 64 VGPR; one raw lgkmcnt barrier).
// Blocks 1..64: W_out -> bf16 conversion (float4-wide) on otherwise-idle CUs,
// hidden entirely under the 576 us GRU scan.
__global__ __attribute__((amdgpu_waves_per_eu(2, 2))) __launch_bounds__(512)
void k_gru(const float* __restrict__ xp, const unsigned short* __restrict__ wfrag,
           const float* __restrict__ b_hh, unsigned short* __restrict__ rnn,
           const float* __restrict__ W_out, unsigned short* __restrict__ woutbf,
           int do_wout) {
    __shared__ unsigned short hbf[2][NBATCH][HB];    // 4096 B, XOR-swizzled

    int tid = threadIdx.x;

    if (blockIdx.x != 0) {
        // -------- woutbf conversion on idle CUs --------
        if (!do_wout) return;
        int bt = (blockIdx.x - 1) * 512 + tid;
        const f32x4* src = (const f32x4*)W_out;
        u16x4* dst = (u16x4*)woutbf;
        for (int qd = bt; qd < NV * HB / 4; qd += 64 * 512) {
            f32x4 v = src[qd];
            u16x4 o;
            o[0] = f2bf(v.x); o[1] = f2bf(v.y); o[2] = f2bf(v.z); o[3] = f2bf(v.w);
            dst[qd] = o;
        }
        return;
    }

    int w = tid >> 6, l = tid & 63;
    int c15 = l & 15, hi = l >> 4;
    int b4 = c15 & 3;
    int q = c15 >> 2;
    int rt = q & 1, jh = q >> 1;
    int swz = (b4 & 1) << 6;

    // r/z -> AGPR (128 = accum half exactly); n -> VGPR (64)
    bf16x8 Arz[2][2][8];
    bf16x8 An[2][8];
    #pragma unroll
    for (int g = 0; g < 2; ++g)
        #pragma unroll
        for (int r2 = 0; r2 < 2; ++r2)
            #pragma unroll
            for (int c = 0; c < 8; ++c) {
                Arz[g][r2][c] = ((const bf16x8*)wfrag)[(((w * 3 + g) * 2 + r2) * 8 + c) * 64 + l];
                asm volatile("" : "+a"(Arz[g][r2][c]));
            }
    #pragma unroll
    for (int r2 = 0; r2 < 2; ++r2)
        #pragma unroll
        for (int c = 0; c < 8; ++c) {
            An[r2][c] = ((const bf16x8*)wfrag)[(((w * 3 + 2) * 2 + r2) * 8 + c) * 64 + l];
            asm volatile("" : "+v"(An[r2][c]));
        }

    for (int k = tid; k < 2 * NBATCH * HB; k += 512) ((unsigned short*)hbf)[k] = 0;

    int row0 = 32 * w + 16 * rt + 4 * hi + 2 * jh;   // lane's 2 rows: row0, row0+1
    f32x2 bn = *(const f32x2*)&b_hh[512 + row0];
    float H0 = 0.f, H1 = 0.f;
    const f32x4 zz = {0.f, 0.f, 0.f, 0.f};

    const float* xpb = xp + (size_t)b4 * SQ * G3 + row0;     // += G3 per step
    unsigned short* rnb = rnn + (size_t)b4 * SQ * HB + row0; // += HB per step
    const char* rdb = (const char*)hbf + b4 * 512;           // + cur + (64c+16hi)^swz
    char* wrb = (char*)hbf + b4 * 512 + ((row0 * 2) ^ swz);  // + nxt
    __syncthreads();

    for (int t = 0; t < SQ; ++t) {
        int cur = (t & 1) << 11, nxt = cur ^ 2048;

        // xp for this step (L2-hit; latency hides under the MFMA cluster)
        f32x2 xr = *(const f32x2*)(xpb);
        f32x2 xz = *(const f32x2*)(xpb + 256);
        f32x2 xn = *(const f32x2*)(xpb + 512);

        f32x4 a0 = zz, a1 = zz, a2 = zz, a3 = zz, a4 = zz, a5 = zz;
        #pragma unroll
        for (int c = 0; c < 8; ++c) {
            bf16x8 Bf = *(const bf16x8*)(rdb + cur + ((64 * c + 16 * hi) ^ swz));
            asm("v_mfma_f32_16x16x32_bf16 %0, %1, %2, %0" : "+v"(a0) : "a"(Arz[0][0][c]), "v"(Bf));
            asm("v_mfma_f32_16x16x32_bf16 %0, %1, %2, %0" : "+v"(a1) : "a"(Arz[0][1][c]), "v"(Bf));
            asm("v_mfma_f32_16x16x32_bf16 %0, %1, %2, %0" : "+v"(a2) : "a"(Arz[1][0][c]), "v"(Bf));
            asm("v_mfma_f32_16x16x32_bf16 %0, %1, %2, %0" : "+v"(a3) : "a"(Arz[1][1][c]), "v"(Bf));
            a4 = __builtin_amdgcn_mfma_f32_16x16x32_bf16(An[0][c], Bf, a4, 0, 0, 0);
            a5 = __builtin_amdgcn_mfma_f32_16x16x32_bf16(An[1][c], Bf, a5, 0, 0, 0);
        }
        // MFMA -> VALU hazard guard for the asm-produced accumulators
        __builtin_amdgcn_sched_barrier(0);
        asm volatile("s_nop 7\n\ts_nop 7");
        __builtin_amdgcn_sched_barrier(0);

        // select this lane's subtile (rt) and component pair (jh)
        bool brt = rt != 0, bjh = jh != 0;
        f32x4 vr = brt ? a1 : a0;
        f32x4 vz = brt ? a3 : a2;
        f32x4 vn = brt ? a5 : a4;
        float sr0 = bjh ? vr.z : vr.x, sr1 = bjh ? vr.w : vr.y;
        float sz0 = bjh ? vz.z : vz.x, sz1 = bjh ? vz.w : vz.y;
        float sn0 = bjh ? vn.z : vn.x, sn1 = bjh ? vn.w : vn.y;

        // gate math: 2 items (rows row0, row0+1), batch b4
        float r0 = __builtin_amdgcn_rcpf(1.f + __expf(-(xr.x + sr0)));
        float z0 = __builtin_amdgcn_rcpf(1.f + __expf(-(xz.x + sz0)));
        float n0 = 1.f - 2.f * __builtin_amdgcn_rcpf(__expf(2.f * (xn.x + r0 * (sn0 + bn.x))) + 1.f);
        float h0 = (1.f - z0) * n0 + z0 * H0;
        H0 = h0;
        float r1 = __builtin_amdgcn_rcpf(1.f + __expf(-(xr.y + sr1)));
        float z1 = __builtin_amdgcn_rcpf(1.f + __expf(-(xz.y + sz1)));
        float n1 = 1.f - 2.f * __builtin_amdgcn_rcpf(__expf(2.f * (xn.y + r1 * (sn1 + bn.y))) + 1.f);
        float h1 = (1.f - z1) * n1 + z1 * H1;
        H1 = h1;

        unsigned int pk;
        asm("v_cvt_pk_bf16_f32 %0, %1, %2" : "=v"(pk) : "v"(h0), "v"(h1));
        *(unsigned int*)(wrb + nxt) = pk;        // LDS h for next step
        *(unsigned int*)rnb = pk;                // global rnn (never drained)

        // raw barrier: only LDS visibility required; global store floats on
        asm volatile("s_waitcnt lgkmcnt(0)" ::: "memory");
        __builtin_amdgcn_sched_barrier(0);
        __builtin_amdgcn_s_barrier();

        xpb += G3;
        rnb += HB;
    }
}

// ---------------------------------------------------------------- K3: logits
// [2048,256] bf16 @ [256,32000] bf16 -> fp32 + bias + mask. XCD-swizzled flat
// grid (T1): all 16 blocks sharing a B-panel (same bx) land on one XCD -> the
// 64 KB panel becomes L2-resident, B re-read traffic 256 MB -> ~16 MB.
template <int CONV>
__global__ __launch_bounds__(256) void k_logits(
        const unsigned short* __restrict__ rnn, const unsigned short* __restrict__ woutbf,
        const float* __restrict__ woutf, const float* __restrict__ b_out,
        const int* __restrict__ x, float* __restrict__ out) {
    // flat fid -> XCD-chunked tile id (4000 = 8 * 500, bijective)
    int fid = blockIdx.x;
    int g = (fid & 7) * 500 + (fid >> 3);
    int bx = g >> 4;          // vocab tile 0..249
    int by = g & 15;          // m tile 0..15

    int tid = threadIdx.x;
    int wv = tid >> 6, l = tid & 63;
    int wm = wv >> 1, wn = wv & 1;
    int c15 = l & 15, hi = l >> 4;
    int m0 = by * 128 + wm * 64;
    int n0 = bx * 128 + wn * 64;

    const f32x4 zz = {0.f, 0.f, 0.f, 0.f};
    f32x4 acc[4][4];
    #pragma unroll
    for (int i = 0; i < 4; ++i)
        #pragma unroll
        for (int j = 0; j < 4; ++j) acc[i][j] = zz;

    #pragma unroll
    for (int c = 0; c < 8; ++c) {
        bf16x8 af[4], bfr[4];
        #pragma unroll
        for (int rt = 0; rt < 4; ++rt)
            af[rt] = *(const bf16x8*)(rnn + (size_t)(m0 + rt * 16 + c15) * HB + 32 * c + 8 * hi);
        #pragma unroll
        for (int ct = 0; ct < 4; ++ct) {
            if (CONV) {
                const float* s = woutf + (size_t)(n0 + ct * 16 + c15) * HB + 32 * c + 8 * hi;
                f32x4 lo = *(const f32x4*)s, hi4 = *(const f32x4*)(s + 4);
                bf16x8 bb;
                #pragma unroll
                for (int qq = 0; qq < 4; ++qq) bb[qq] = (short)f2bf(lo[qq]);
                #pragma unroll
                for (int qq = 0; qq < 4; ++qq) bb[4 + qq] = (short)f2bf(hi4[qq]);
                bfr[ct] = bb;
            } else {
                bfr[ct] = *(const bf16x8*)(woutbf + (size_t)(n0 + ct * 16 + c15) * HB + 32 * c + 8 * hi);
            }
        }
        #pragma unroll
        for (int rt = 0; rt < 4; ++rt)
            #pragma unroll
            for (int ct = 0; ct < 4; ++ct)
                acc[rt][ct] = __builtin_amdgcn_mfma_f32_16x16x32_bf16(af[rt], bfr[ct], acc[rt][ct], 0, 0, 0);
    }

    float bo[4];
    #pragma unroll
    for (int ct = 0; ct < 4; ++ct) bo[ct] = b_out[n0 + ct * 16 + c15];

    const float NEGINF = -__builtin_inff();
    #pragma unroll
    for (int rt = 0; rt < 4; ++rt) {
        #pragma unroll
        for (int j = 0; j < 4; ++j) {
            int m = m0 + rt * 16 + 4 * hi + j;
            int tt = m & (SQ - 1);
            bool bad = (tt > 0) && (x[m - 1] == 0);
            float* orow = out + (size_t)m * NV;
            #pragma unroll
            for (int ct = 0; ct < 4; ++ct) {
                int v = n0 + ct * 16 + c15;
                float val = acc[rt][ct][j] + bo[ct];
                if (bad && v >= 3) val = NEGINF;
                orow[v] = val;
            }
        }
    }
}

extern "C" void kernel_launch(void* const* d_in, const int* in_sizes, int n_in,
                              void* d_out, int out_size, void* d_ws, size_t ws_size,
                              hipStream_t stream) {
    const int*   x     = (const int*)d_in[0];
    const float* emb   = (const float*)d_in[1];
    const float* W_ih  = (const float*)d_in[2];
    const float* W_hh  = (const float*)d_in[3];
    const float* b_ih  = (const float*)d_in[4];
    const float* b_hh  = (const float*)d_in[5];
    const float* W_out = (const float*)d_in[6];
    const float* b_out = (const float*)d_in[7];
    float* out = (float*)d_out;

    char* ws = (char*)d_ws;
    float*          xp     = (float*)(ws);                       // 6,291,456 B
    float*          w_ihT  = (float*)(ws + 6291456);             // 786,432 B
    unsigned short* wfrag  = (unsigned short*)(ws + 7077888);    // 393,216 B
    unsigned short* rnn    = (unsigned short*)(ws + 7471104);    // 1,048,576 B
    unsigned short* woutbf = (unsigned short*)(ws + 8519680);    // 16,384,000 B
    int use_woutbf = (ws_size >= (size_t)24903680) ? 1 : 0;

    k_prep<<<512, 256, 0, stream>>>(W_ih, W_hh, w_ihT, wfrag);
    k_embed_xp<<<512, 256, 0, stream>>>(x, emb, w_ihT, b_ih, b_hh, xp);
    k_gru<<<65, 512, 0, stream>>>(xp, wfrag, b_hh, rnn, W_out, woutbf, use_woutbf);
    if (use_woutbf)
        k_logits<0><<<4000, 256, 0, stream>>>(rnn, woutbf, nullptr, b_out, x, out);
    else
        k_logits<1><<<4000, 256, 0, stream>>>(rnn, nullptr, W_out, b_out, x, out);
}